// Round 1
// baseline (274.426 us; speedup 1.0000x reference)
//
#include <hip/hip_runtime.h>

// ProbasLinear (NoisyNet-style) training forward:
// out[b,o] = sum_i x[b,i]*(wmu[o,i] + |wsig[o,i]|*eps_w[b,o,i])
//          + bmu[o] + |bsig[o]|*eps_b[b,o]
// B=1024, OUT=512, IN=512, all fp32.
// Memory-bound on the 1 GiB eps_w stream -> one wave per (b,o) row,
// float4 coalesced loads, fp32 wave reduction.

constexpr int B_DIM  = 1024;
constexpr int OUT_DIM = 512;
constexpr int IN_DIM  = 512;

__global__ __launch_bounds__(256) void probas_linear_kernel(
    const float* __restrict__ x,       // [B, IN]
    const float* __restrict__ wmu,     // [OUT, IN]
    const float* __restrict__ wsig,    // [OUT, IN]
    const float* __restrict__ bmu,     // [OUT]
    const float* __restrict__ bsig,    // [OUT]
    const float* __restrict__ epsw,    // [B, OUT, IN]
    const float* __restrict__ epsb,    // [B, OUT]
    float* __restrict__ out)           // [B, OUT]
{
    const int wave_in_block = threadIdx.x >> 6;
    const int lane = threadIdx.x & 63;
    const long long row = (long long)blockIdx.x * 4 + wave_in_block; // b*OUT + o
    const int b = (int)(row >> 9);   // / OUT_DIM (512)
    const int o = (int)(row & 511);  // % OUT_DIM

    const float4* __restrict__ ev = (const float4*)(epsw + row * IN_DIM);
    const float4* __restrict__ xv = (const float4*)(x + (long long)b * IN_DIM);
    const float4* __restrict__ mv = (const float4*)(wmu + (long long)o * IN_DIM);
    const float4* __restrict__ sv = (const float4*)(wsig + (long long)o * IN_DIM);

    float acc = 0.0f;
    // 512 floats = 128 float4 per row; 64 lanes -> 2 float4 each, coalesced.
    #pragma unroll
    for (int r = 0; r < 2; ++r) {
        const int idx = lane + r * 64;
        const float4 e  = ev[idx];
        const float4 xx = xv[idx];
        const float4 m  = mv[idx];
        const float4 s  = sv[idx];
        acc += xx.x * (m.x + fabsf(s.x) * e.x);
        acc += xx.y * (m.y + fabsf(s.y) * e.y);
        acc += xx.z * (m.z + fabsf(s.z) * e.z);
        acc += xx.w * (m.w + fabsf(s.w) * e.w);
    }

    // 64-lane butterfly reduction
    #pragma unroll
    for (int off = 32; off > 0; off >>= 1)
        acc += __shfl_down(acc, off, 64);

    if (lane == 0) {
        const float bias = bmu[o] + fabsf(bsig[o]) * epsb[row];
        out[row] = acc + bias;
    }
}

extern "C" void kernel_launch(void* const* d_in, const int* in_sizes, int n_in,
                              void* d_out, int out_size, void* d_ws, size_t ws_size,
                              hipStream_t stream) {
    const float* x    = (const float*)d_in[0];
    const float* wmu  = (const float*)d_in[1];
    const float* wsig = (const float*)d_in[2];
    const float* bmu  = (const float*)d_in[3];
    const float* bsig = (const float*)d_in[4];
    const float* epsw = (const float*)d_in[5];
    const float* epsb = (const float*)d_in[6];
    float* out = (float*)d_out;

    const int total_rows = B_DIM * OUT_DIM;        // 524288
    const int rows_per_block = 4;                  // 4 waves/block
    dim3 grid(total_rows / rows_per_block);        // 131072
    dim3 block(256);
    probas_linear_kernel<<<grid, block, 0, stream>>>(
        x, wmu, wsig, bmu, bsig, epsw, epsb, out);
}

// Round 2
// 199.948 us; speedup vs baseline: 1.3725x; 1.3725x over previous
//
#include <hip/hip_runtime.h>

// ProbasLinear training forward, fp32:
// out[b,o] = sum_i x[b,i]*(wmu[o,i] + |wsig[o,i]|*eps_w[b,o,i])
//          + bmu[o] + |bsig[o]|*eps_b[b,o]
// B=1024, OUT=512, IN=512.
// HBM-bound on the 1 GiB eps_w stream. One wave per 2x2 (b,o) tile:
// x reused across o, wmu/wsig reused across b -> cached re-read traffic
// halved vs 1 row/wave. eps_w loaded nontemporally (read-once stream,
// keep L2 for x/mu/sigma). 4 independent shuffle-reduction chains.

typedef float v4f __attribute__((ext_vector_type(4)));

constexpr int B_DIM   = 1024;
constexpr int OUT_DIM = 512;
constexpr int IN_DIM  = 512;
constexpr int ROW_V4  = IN_DIM / 4;   // 128 float4 per row

__device__ __forceinline__ v4f ntload(const v4f* p) {
    return __builtin_nontemporal_load(p);
}

__global__ __launch_bounds__(256) void probas_linear_kernel(
    const float* __restrict__ x,       // [B, IN]
    const float* __restrict__ wmu,     // [OUT, IN]
    const float* __restrict__ wsig,    // [OUT, IN]
    const float* __restrict__ bmu,     // [OUT]
    const float* __restrict__ bsig,    // [OUT]
    const float* __restrict__ epsw,    // [B, OUT, IN]
    const float* __restrict__ epsb,    // [B, OUT]
    float* __restrict__ out)           // [B, OUT]
{
    const int wave = threadIdx.x >> 6;
    const int lane = threadIdx.x & 63;
    const int wid  = blockIdx.x * 4 + wave;      // [0, 131072)
    const int tb   = wid >> 8;                   // 512 b-tiles
    const int to   = wid & 255;                  // 256 o-tiles
    const int b0   = tb * 2;
    const int o0   = to * 2;

    const v4f* __restrict__ xv0 = (const v4f*)(x + (size_t)b0 * IN_DIM);
    const v4f* __restrict__ xv1 = xv0 + ROW_V4;
    const v4f* __restrict__ mv0 = (const v4f*)(wmu + (size_t)o0 * IN_DIM);
    const v4f* __restrict__ mv1 = mv0 + ROW_V4;
    const v4f* __restrict__ sv0 = (const v4f*)(wsig + (size_t)o0 * IN_DIM);
    const v4f* __restrict__ sv1 = sv0 + ROW_V4;

    const size_t row00 = (size_t)b0 * OUT_DIM + o0;        // flat (b0,o0)
    const v4f* __restrict__ ebase = (const v4f*)(epsw) + row00 * ROW_V4;
    constexpr size_t E_BSTRIDE = (size_t)OUT_DIM * ROW_V4; // v4f per b step

    float acc00 = 0.f, acc01 = 0.f, acc10 = 0.f, acc11 = 0.f;

    #pragma unroll
    for (int r = 0; r < 2; ++r) {
        const int idx = lane + r * 64;             // 128 v4f per row, 64 lanes
        const v4f e00 = ntload(ebase + idx);                       // (b0 ,o0 )
        const v4f e01 = ntload(ebase + ROW_V4 + idx);              // (b0 ,o0+1)
        const v4f e10 = ntload(ebase + E_BSTRIDE + idx);           // (b0+1,o0 )
        const v4f e11 = ntload(ebase + E_BSTRIDE + ROW_V4 + idx);  // (b0+1,o0+1)
        const v4f xa = xv0[idx];
        const v4f xb = xv1[idx];
        const v4f m0 = mv0[idx];
        const v4f m1 = mv1[idx];
        const v4f s0 = sv0[idx];
        const v4f s1 = sv1[idx];
        #pragma unroll
        for (int j = 0; j < 4; ++j) {
            const float as0 = fabsf(s0[j]);
            const float as1 = fabsf(s1[j]);
            acc00 += xa[j] * (m0[j] + as0 * e00[j]);
            acc01 += xa[j] * (m1[j] + as1 * e01[j]);
            acc10 += xb[j] * (m0[j] + as0 * e10[j]);
            acc11 += xb[j] * (m1[j] + as1 * e11[j]);
        }
    }

    // 4 independent 64-lane butterfly reductions (chains interleave)
    #pragma unroll
    for (int off = 32; off > 0; off >>= 1) {
        acc00 += __shfl_down(acc00, off, 64);
        acc01 += __shfl_down(acc01, off, 64);
        acc10 += __shfl_down(acc10, off, 64);
        acc11 += __shfl_down(acc11, off, 64);
    }

    if (lane == 0) {
        const float bm0 = bmu[o0],  bm1 = bmu[o0 + 1];
        const float bs0 = fabsf(bsig[o0]), bs1 = fabsf(bsig[o0 + 1]);
        const float* eb = epsb + (size_t)b0 * OUT_DIM + o0;
        out[row00]               = acc00 + bm0 + bs0 * eb[0];
        out[row00 + 1]           = acc01 + bm1 + bs1 * eb[1];
        out[row00 + OUT_DIM]     = acc10 + bm0 + bs0 * eb[OUT_DIM];
        out[row00 + OUT_DIM + 1] = acc11 + bm1 + bs1 * eb[OUT_DIM + 1];
    }
}

extern "C" void kernel_launch(void* const* d_in, const int* in_sizes, int n_in,
                              void* d_out, int out_size, void* d_ws, size_t ws_size,
                              hipStream_t stream) {
    const float* x    = (const float*)d_in[0];
    const float* wmu  = (const float*)d_in[1];
    const float* wsig = (const float*)d_in[2];
    const float* bmu  = (const float*)d_in[3];
    const float* bsig = (const float*)d_in[4];
    const float* epsw = (const float*)d_in[5];
    const float* epsb = (const float*)d_in[6];
    float* out = (float*)d_out;

    const int total_tiles = (B_DIM / 2) * (OUT_DIM / 2); // 131072 waves
    dim3 grid(total_tiles / 4);                          // 32768 blocks, 4 waves each
    dim3 block(256);
    probas_linear_kernel<<<grid, block, 0, stream>>>(
        x, wmu, wsig, bmu, bsig, epsw, epsb, out);
}

// Round 3
// 167.572 us; speedup vs baseline: 1.6377x; 1.1932x over previous
//
#include <hip/hip_runtime.h>

// ProbasLinear training forward, fp32:
// out[b,o] = sum_i x[b,i]*(wmu[o,i] + |wsig[o,i]|*eps_w[b,o,i])
//          + bmu[o] + |bsig[o]|*eps_b[b,o]
// B=1024, OUT=512, IN=512.
// HBM-bound on the 1 GiB eps_w stream (read exactly once).
// One wave per 4x4 (b,o) tile: x reused 4x across o, wmu/wsig reused 4x
// across b -> cached re-read traffic 768 MiB (vs 1.5 GiB at 2x2).
// eps_w loaded nontemporally (read-once stream, preserve L2 for x/mu/sig).
// 16 independent accumulator/reduction chains (statically indexed -> regs).

typedef float v4f __attribute__((ext_vector_type(4)));

constexpr int B_DIM   = 1024;
constexpr int OUT_DIM = 512;
constexpr int IN_DIM  = 512;
constexpr int ROW_V4  = IN_DIM / 4;   // 128 float4 per row
constexpr int TB = 4;                 // b-tile per wave
constexpr int TO = 4;                 // o-tile per wave

__device__ __forceinline__ v4f ntload(const v4f* p) {
    return __builtin_nontemporal_load(p);
}

__global__ __launch_bounds__(256) void probas_linear_kernel(
    const float* __restrict__ x,       // [B, IN]
    const float* __restrict__ wmu,     // [OUT, IN]
    const float* __restrict__ wsig,    // [OUT, IN]
    const float* __restrict__ bmu,     // [OUT]
    const float* __restrict__ bsig,    // [OUT]
    const float* __restrict__ epsw,    // [B, OUT, IN]
    const float* __restrict__ epsb,    // [B, OUT]
    float* __restrict__ out)           // [B, OUT]
{
    const int wave = threadIdx.x >> 6;
    const int lane = threadIdx.x & 63;
    const int wid  = blockIdx.x * 4 + wave;          // [0, 32768)
    const int tb   = wid >> 7;                       // 256 b-tiles
    const int to   = wid & 127;                      // 128 o-tiles
    const int b0   = tb * TB;
    const int o0   = to * TO;

    const v4f* __restrict__ xv = (const v4f*)(x + (size_t)b0 * IN_DIM);
    const v4f* __restrict__ mv = (const v4f*)(wmu + (size_t)o0 * IN_DIM);
    const v4f* __restrict__ sv = (const v4f*)(wsig + (size_t)o0 * IN_DIM);

    const size_t row00 = (size_t)b0 * OUT_DIM + o0;        // flat (b0,o0)
    const v4f* __restrict__ ebase = (const v4f*)(epsw) + row00 * ROW_V4;
    constexpr size_t E_BSTRIDE = (size_t)OUT_DIM * ROW_V4; // v4f per b step

    float acc[TB][TO];
    #pragma unroll
    for (int bi = 0; bi < TB; ++bi)
        #pragma unroll
        for (int oi = 0; oi < TO; ++oi) acc[bi][oi] = 0.f;

    #pragma unroll
    for (int r = 0; r < 2; ++r) {
        const int idx = lane + r * 64;              // 128 v4f per row

        // issue all 16 HBM streams first (deep MLP), then cached loads
        v4f e[TB][TO];
        #pragma unroll
        for (int bi = 0; bi < TB; ++bi)
            #pragma unroll
            for (int oi = 0; oi < TO; ++oi)
                e[bi][oi] = ntload(ebase + (size_t)bi * E_BSTRIDE
                                         + (size_t)oi * ROW_V4 + idx);

        v4f xa[TB], m[TO], s[TO];
        #pragma unroll
        for (int bi = 0; bi < TB; ++bi) xa[bi] = xv[(size_t)bi * ROW_V4 + idx];
        #pragma unroll
        for (int oi = 0; oi < TO; ++oi) {
            m[oi] = mv[(size_t)oi * ROW_V4 + idx];
            s[oi] = sv[(size_t)oi * ROW_V4 + idx];
        }

        #pragma unroll
        for (int j = 0; j < 4; ++j) {
            float as[TO];
            #pragma unroll
            for (int oi = 0; oi < TO; ++oi) as[oi] = fabsf(s[oi][j]);
            #pragma unroll
            for (int bi = 0; bi < TB; ++bi)
                #pragma unroll
                for (int oi = 0; oi < TO; ++oi)
                    acc[bi][oi] += xa[bi][j] * (m[oi][j] + as[oi] * e[bi][oi][j]);
        }
    }

    // 16 independent 64-lane butterfly reductions
    #pragma unroll
    for (int off = 32; off > 0; off >>= 1)
        #pragma unroll
        for (int bi = 0; bi < TB; ++bi)
            #pragma unroll
            for (int oi = 0; oi < TO; ++oi)
                acc[bi][oi] += __shfl_down(acc[bi][oi], off, 64);

    if (lane == 0) {
        #pragma unroll
        for (int bi = 0; bi < TB; ++bi) {
            const float* eb = epsb + (size_t)(b0 + bi) * OUT_DIM + o0;
            float* op = out + (size_t)(b0 + bi) * OUT_DIM + o0;
            #pragma unroll
            for (int oi = 0; oi < TO; ++oi)
                op[oi] = acc[bi][oi] + bmu[o0 + oi]
                       + fabsf(bsig[o0 + oi]) * eb[oi];
        }
    }
}

extern "C" void kernel_launch(void* const* d_in, const int* in_sizes, int n_in,
                              void* d_out, int out_size, void* d_ws, size_t ws_size,
                              hipStream_t stream) {
    const float* x    = (const float*)d_in[0];
    const float* wmu  = (const float*)d_in[1];
    const float* wsig = (const float*)d_in[2];
    const float* bmu  = (const float*)d_in[3];
    const float* bsig = (const float*)d_in[4];
    const float* epsw = (const float*)d_in[5];
    const float* epsb = (const float*)d_in[6];
    float* out = (float*)d_out;

    const int total_waves = (B_DIM / TB) * (OUT_DIM / TO); // 32768
    dim3 grid(total_waves / 4);                            // 8192 blocks
    dim3 block(256);
    probas_linear_kernel<<<grid, block, 0, stream>>>(
        x, wmu, wsig, bmu, bsig, epsw, epsb, out);
}